// Round 11
// baseline (161.107 us; speedup 1.0000x reference)
//
#include <hip/hip_runtime.h>
#include <hip/hip_bf16.h>
#include <math.h>

typedef __attribute__((ext_vector_type(8))) __bf16 bf16x8;
typedef __attribute__((ext_vector_type(4))) float f32x4;

#define S_LEN 1024
#define D_MODEL 384
#define BATCH 32
#define N3 1152
#define KVB 64
#define NT (S_LEN / KVB)

#define MFMA16(a, b, c) __builtin_amdgcn_mfma_f32_16x16x32_bf16((a), (b), (c), 0, 0, 0)

static __device__ __forceinline__ ushort f2bf(float f) {
    __bf16 h = (__bf16)f;
    return __builtin_bit_cast(ushort, h);
}
static __device__ __forceinline__ float exp2a(float x) {
    float r; asm("v_exp_f32 %0, %1" : "=v"(r) : "v"(x)); return r;
}
static __device__ __forceinline__ uint cvtpk(float a, float b) {
    uint r; asm("v_cvt_pk_bf16_f32 %0, %1, %2" : "=v"(r) : "v"(a), "v"(b)); return r;
}

// ---------------- kernel 1: positional-encoding table, transposed peT[k][s] ----
__global__ void pe_kernel(float* peT) {
    int idx = blockIdx.x * 256 + threadIdx.x;      // 384*1024 total
    int k = idx >> 10, s = idx & 1023;
    float e = -(float)((k >> 1) * 2) * (logf(10000.0f) / (float)D_MODEL);
    float div = expf(e);
    float a = (float)s * div;
    peT[idx] = (k & 1) ? cosf(a) : sinf(a);
}

// ---------------- kernel 2: W [384][1152] f32 -> Wt [1152][384] bf16 ----------
__global__ void wt_kernel(const float* __restrict__ W, ushort* __restrict__ Wt) {
    __shared__ float tile[32][33];
    int n0 = blockIdx.x * 32, k0 = blockIdx.y * 32;
    int tx = threadIdx.x, ty = threadIdx.y;
#pragma unroll
    for (int r = 0; r < 4; ++r) {
        int kl = ty * 4 + r;
        tile[kl][tx] = W[(size_t)(k0 + kl) * N3 + n0 + tx];
    }
    __syncthreads();
#pragma unroll
    for (int r = 0; r < 4; ++r) {
        int nl = ty * 4 + r;
        Wt[(size_t)(n0 + nl) * D_MODEL + k0 + tx] = f2bf(tile[tx][nl]);
    }
}

// ---------------- kernel 3: A[m][k] = bf16(x[b][k][s] + peT[k][s]) ------------
__global__ void astage_kernel(const float* __restrict__ x, const float* __restrict__ peT,
                              ushort* __restrict__ A) {
    __shared__ float tile[32][33];
    int s0 = blockIdx.x * 32, k0 = blockIdx.y * 32, b = blockIdx.z;
    int tx = threadIdx.x, ty = threadIdx.y;
#pragma unroll
    for (int r = 0; r < 4; ++r) {
        int kl = ty * 4 + r;
        tile[kl][tx] = x[(size_t)(b * D_MODEL + k0 + kl) * S_LEN + s0 + tx]
                     + peT[(size_t)(k0 + kl) * S_LEN + s0 + tx];
    }
    __syncthreads();
#pragma unroll
    for (int r = 0; r < 4; ++r) {
        int sl = ty * 4 + r;
        A[(size_t)(b * S_LEN + s0 + sl) * D_MODEL + k0 + tx] = f2bf(tile[tx][sl]);
    }
}

// ---------------- kernel 4: qkv GEMM -> Q rows + 64-kv pre-tiled/swizzled K,V
// K_tiled[b][t16][j 64][384k]: row 768B, 16B-slot XOR (k>>3)^(j&7) baked.
// V_tiled[b][t16][c 384][j 64]: row 128B, 16B-slot XOR (j>>3)^(c&7) baked.
// Panels 48 KB contiguous -> attn staging is a linear coalesced memcpy.
__global__ __launch_bounds__(256) void qkv_gemm(const ushort* __restrict__ A,
                                                const ushort* __restrict__ Wt,
                                                const float* __restrict__ bias,
                                                ushort* __restrict__ Qb,
                                                ushort* __restrict__ Ktl,
                                                ushort* __restrict__ Vtl) {
    __shared__ __align__(16) ushort As[128 * 32];
    __shared__ __align__(16) ushort Bs[128 * 32];
    int id = blockIdx.x;                  // 2304 = 8 chunks * (9 n * 32 m)
    int g = id / 288, loc = id % 288;
    int nt_ = loc / 32, mt_ = g * 32 + (loc % 32);
    int m0 = mt_ * 128, n0 = nt_ * 128;
    int tid = threadIdx.x;
    int wave = tid >> 6, lane = tid & 63;
    int i16 = lane & 15, gq = lane >> 4;
    int wr = wave >> 1, wc = wave & 1;
    f32x4 acc[4][4] = {};
    for (int ks = 0; ks < 12; ++ks) {
        int k0 = ks * 32;
        __syncthreads();
#pragma unroll
        for (int i = 0; i < 2; ++i) {
            int off = (wave * 2 + i) * 1024;
            int row = (off >> 6) + (lane >> 2);
            int kc = lane & 3;
            const ushort* ga = A + (size_t)(m0 + row) * D_MODEL + k0 + kc * 8;
            __builtin_amdgcn_global_load_lds(
                (const __attribute__((address_space(1))) uint32_t*)ga,
                (__attribute__((address_space(3))) uint32_t*)((char*)As + off), 16, 0, 0);
            const ushort* gb = Wt + (size_t)(n0 + row) * D_MODEL + k0 + kc * 8;
            __builtin_amdgcn_global_load_lds(
                (const __attribute__((address_space(1))) uint32_t*)gb,
                (__attribute__((address_space(3))) uint32_t*)((char*)Bs + off), 16, 0, 0);
        }
        __syncthreads();
        bf16x8 af[4], bfr[4];
#pragma unroll
        for (int mt = 0; mt < 4; ++mt) {
            int row = wr * 64 + mt * 16 + i16;
            af[mt] = *reinterpret_cast<const bf16x8*>(&As[row * 32 + gq * 8]);
        }
#pragma unroll
        for (int nt = 0; nt < 4; ++nt) {
            int row = wc * 64 + nt * 16 + i16;
            bfr[nt] = *reinterpret_cast<const bf16x8*>(&Bs[row * 32 + gq * 8]);
        }
#pragma unroll
        for (int mt = 0; mt < 4; ++mt)
#pragma unroll
            for (int nt = 0; nt < 4; ++nt)
                acc[mt][nt] = MFMA16(af[mt], bfr[nt], acc[mt][nt]);
    }
    if (n0 < D_MODEL) {
        // Q range: compact rows Qb[m][0..384)
#pragma unroll
        for (int nt = 0; nt < 4; ++nt) {
            int n = n0 + wc * 64 + nt * 16 + i16;
            float bv = bias[n];
#pragma unroll
            for (int mt = 0; mt < 4; ++mt)
#pragma unroll
                for (int r = 0; r < 4; ++r) {
                    int m = m0 + wr * 64 + mt * 16 + gq * 4 + r;
                    Qb[(size_t)m * D_MODEL + n] = f2bf(acc[mt][nt][r] + bv);
                }
        }
    } else if (n0 < 2 * D_MODEL) {
        // K range -> 64-kv K panels, swizzle baked
        int b = m0 >> 10;
#pragma unroll
        for (int nt = 0; nt < 4; ++nt) {
            int n = n0 + wc * 64 + nt * 16 + i16;
            float bv = bias[n];
            int k2 = n - D_MODEL;                 // 0..383
            int slotk = k2 >> 3, within = k2 & 7;
#pragma unroll
            for (int mt = 0; mt < 4; ++mt)
#pragma unroll
                for (int r = 0; r < 4; ++r) {
                    int m = m0 + wr * 64 + mt * 16 + gq * 4 + r;
                    int s = m & 1023;
                    int t = s >> 6, j = s & 63;
                    size_t idx = (size_t)(b * 16 + t) * 24576 + j * 384
                               + (((slotk ^ (j & 7)) << 3) + within);
                    Ktl[idx] = f2bf(acc[mt][nt][r] + bv);
                }
        }
    } else {
        // V range -> 64-kv V panels, swizzle baked (4 consecutive s per ushort4)
        int b = m0 >> 10;
#pragma unroll
        for (int nt = 0; nt < 4; ++nt) {
            int n = n0 + wc * 64 + nt * 16 + i16;
            float bv = bias[n];
            int c = n - 2 * D_MODEL;
            int cx = c & 7;
#pragma unroll
            for (int mt = 0; mt < 4; ++mt) {
                int m = m0 + wr * 64 + mt * 16 + gq * 4;
                int s = m & 1023;
                int t = s >> 6, j = s & 63;       // j % 4 == 0
                size_t idx = (size_t)(b * 16 + t) * 24576 + c * 64
                           + ((((j >> 3) ^ cx) << 3) + (j & 7));
                ushort4 p4;
                p4.x = f2bf(acc[mt][nt][0] + bv);
                p4.y = f2bf(acc[mt][nt][1] + bv);
                p4.z = f2bf(acc[mt][nt][2] + bv);
                p4.w = f2bf(acc[mt][nt][3] + bv);
                *reinterpret_cast<ushort4*>(&Vtl[idx]) = p4;
            }
        }
    }
}

// ---------------- kernel 5: flash attention v10b (compile-fixed) -------------
// m214-family structure: KVB=64, 8 waves = 4 qg (16 q) x 2 h (j-half 32).
// Each wave: S[32 j][16 q] (24 MFMA), in-register P (v4 shuffle redistribution,
// NO P LDS / NO mid-tile P barrier), partial O over its j-half (PV k=32, full
// c=384, 96 acc VGPR). h-halves summed once in epilogue via reused LDS.
// K single (48K) + V double (96K) = 144 KB. 2 light barriers per 64 kv.
// V-buffer address computed arithmetically (no LDS pointer array - R10 error).
__global__ __launch_bounds__(512, 2) void attn_kernel(const ushort* __restrict__ Qb,
                                                      const ushort* __restrict__ Ktl,
                                                      const ushort* __restrict__ Vtl,
                                                      float* __restrict__ out) {
    __shared__ __align__(16) char smem[49152 * 3 + 512];
    int id = blockIdx.x;                               // 512 = 16 qt * 4 slot * 8 xcd
    int xcd = id & 7, slot = (id >> 3) & 3, qt = id >> 5;
    int b = slot * 8 + xcd;                            // batch grouped per XCD
    int tid = threadIdx.x;
    int wave = tid >> 6, lane = tid & 63;
    int i16 = lane & 15, gq = lane >> 4;
    int qg = wave & 3, h = wave >> 2;
    int q0w = qt * 64 + qg * 16;

    auto stage_K = [&](int tt) {
        const ushort* pan = Ktl + (size_t)(b * 16 + tt) * 24576;
#pragma unroll
        for (int r = 0; r < 6; ++r) {
            int ii = wave * 6 + r;                     // 0..47
            const ushort* ga = pan + ii * 512 + lane * 8;
            __builtin_amdgcn_global_load_lds(
                (const __attribute__((address_space(1))) uint32_t*)ga,
                (__attribute__((address_space(3))) uint32_t*)(smem + ii * 1024), 16, 0, 0);
        }
    };
    auto stage_V = [&](int tt, int bi) {
        const ushort* pan = Vtl + (size_t)(b * 16 + tt) * 24576;
        char* dst = smem + 49152 + bi * 49152;
#pragma unroll
        for (int r = 0; r < 6; ++r) {
            int ii = wave * 6 + r;
            const ushort* ga = pan + ii * 512 + lane * 8;
            __builtin_amdgcn_global_load_lds(
                (const __attribute__((address_space(1))) uint32_t*)ga,
                (__attribute__((address_space(3))) uint32_t*)(dst + ii * 1024), 16, 0, 0);
        }
    };

    stage_K(0);
    stage_V(0, 0);

    // Q fragments (B-operand): lane (gq,i16): Q[q0w + i16][kt*32 + gq*8 ..+8]
    bf16x8 qf[12];
    const ushort* Qr = Qb + (size_t)(b * S_LEN + q0w + i16) * D_MODEL;
#pragma unroll
    for (int kt = 0; kt < 12; ++kt)
        qf[kt] = *reinterpret_cast<const bf16x8*>(Qr + kt * 32 + gq * 8);

    f32x4 oc[24] = {};
    float lsum = 0.f;
    const float sl2e = 0.05103103630798287f * 1.4426950408889634f;
    const int sw = i16 & 7;                        // slot XOR (j&7 == c&7 == i16&7)
    const int jb = h * 32;
    const int srcA = ((gq & 1) << 5) + i16;        // v4 redistribution sources
    const int srcB = srcA + 16;
    const int jhsel = gq >> 1;

    for (int t = 0; t < NT; ++t) {
        asm volatile("s_waitcnt vmcnt(0) lgkmcnt(0)" ::: "memory");  // K(t),V(t) landed
        __builtin_amdgcn_s_barrier();                                // B1
        __builtin_amdgcn_sched_barrier(0);

        // ---- QK: S[jb..jb+32][16 q] ----
        const char* Kb = (const char*)smem;
        f32x4 sacc0 = {}, sacc1 = {};
        __builtin_amdgcn_s_setprio(1);
#pragma unroll
        for (int kt = 0; kt < 12; ++kt) {
            const char* k0p = Kb + (jb + i16) * 768 + (((kt * 4 + gq) ^ sw) << 4);
            const char* k1p = Kb + (jb + 16 + i16) * 768 + (((kt * 4 + gq) ^ sw) << 4);
            bf16x8 kf0 = *reinterpret_cast<const bf16x8*>(k0p);
            bf16x8 kf1 = *reinterpret_cast<const bf16x8*>(k1p);
            sacc0 = MFMA16(kf0, qf[kt], sacc0);
            sacc1 = MFMA16(kf1, qf[kt], sacc1);
        }
        __builtin_amdgcn_s_setprio(0);

        // ---- p = exp2(s*scale*log2e) (drop-max), lane q = i16 ----
        float p00 = exp2a(sacc0[0] * sl2e), p01 = exp2a(sacc0[1] * sl2e);
        float p02 = exp2a(sacc0[2] * sl2e), p03 = exp2a(sacc0[3] * sl2e);
        float p10 = exp2a(sacc1[0] * sl2e), p11 = exp2a(sacc1[1] * sl2e);
        float p12 = exp2a(sacc1[2] * sl2e), p13 = exp2a(sacc1[3] * sl2e);
        lsum += ((p00 + p01) + (p02 + p03)) + ((p10 + p11) + (p12 + p13));

        // ---- in-register P -> PV B-frag (8 shfl + 4 selects, v4-verified) ----
        uint u00 = cvtpk(p00, p01), u01 = cvtpk(p02, p03);
        uint u10 = cvtpk(p10, p11), u11 = cvtpk(p12, p13);
        uint tA0 = __shfl(u00, srcA, 64), tA1 = __shfl(u10, srcA, 64);
        uint tA2 = __shfl(u01, srcA, 64), tA3 = __shfl(u11, srcA, 64);
        uint tB0 = __shfl(u00, srcB, 64), tB1 = __shfl(u10, srcB, 64);
        uint tB2 = __shfl(u01, srcB, 64), tB3 = __shfl(u11, srcB, 64);
        uint4 wv;
        wv.x = jhsel ? tA1 : tA0;
        wv.y = jhsel ? tA3 : tA2;
        wv.z = jhsel ? tB1 : tB0;
        wv.w = jhsel ? tB3 : tB2;
        bf16x8 pf = __builtin_bit_cast(bf16x8, wv);

        asm volatile("s_waitcnt lgkmcnt(0)" ::: "memory");   // my K reads retired
        __builtin_amdgcn_s_barrier();                        // B2: all K reads done
        __builtin_amdgcn_sched_barrier(0);
        if (t + 1 < NT) {                                    // covered by PV below
            stage_K(t + 1);
            stage_V(t + 1, (t + 1) & 1);
        }

        // ---- PV: O_h[384 c][16 q] += V[j-half] . P (k=32) ----
        const char* Vb = smem + 49152 + (t & 1) * 49152;
        __builtin_amdgcn_s_setprio(1);
#pragma unroll
        for (int ct = 0; ct < 24; ++ct) {
            const char* vp = Vb + (ct * 16 + i16) * 128 + (((h * 4 + gq) ^ sw) << 4);
            bf16x8 vf = *reinterpret_cast<const bf16x8*>(vp);
            oc[ct] = MFMA16(vf, pf, oc[ct]);
        }
        __builtin_amdgcn_s_setprio(0);
    }

    // ---- epilogue: combine h-halves via reused LDS ----
    lsum += __shfl_xor(lsum, 16);
    lsum += __shfl_xor(lsum, 32);          // all lanes: h-half l for q=i16
    __syncthreads();                       // all PV reads done; K/V space dead
    float* Ored = (float*)smem;            // [4 qg][384 c][16 q] = 96 KB
    float* Lred = (float*)(smem + 98304);  // [4 qg][16 q]
    if (h == 0) {
        float* Oq = Ored + qg * 6144;
#pragma unroll
        for (int ct = 0; ct < 24; ++ct)
#pragma unroll
            for (int r = 0; r < 4; ++r)
                Oq[(ct * 16 + gq * 4 + r) * 16 + i16] = oc[ct][r];
        if (gq == 0) Lred[qg * 16 + i16] = lsum;
    }
    __syncthreads();
    if (h == 1) {
        const float* Oq = Ored + qg * 6144;
        float inv = 1.0f / (lsum + Lred[qg * 16 + i16]);
        float* ob = out + (size_t)b * D_MODEL * S_LEN + q0w + i16;
#pragma unroll
        for (int ct = 0; ct < 24; ++ct)
#pragma unroll
            for (int r = 0; r < 4; ++r) {
                int c = ct * 16 + gq * 4 + r;
                ob[(size_t)c * S_LEN] = (oc[ct][r] + Oq[c * 16 + i16]) * inv;
            }
    }
}

extern "C" void kernel_launch(void* const* d_in, const int* in_sizes, int n_in,
                              void* d_out, int out_size, void* d_ws, size_t ws_size,
                              hipStream_t stream) {
    const float* x    = (const float*)d_in[0];
    const float* W    = (const float*)d_in[1];
    const float* bias = (const float*)d_in[2];
    float* out = (float*)d_out;

    char* ws = (char*)d_ws;
    ushort* A_bf = (ushort*)(ws);                // 25,165,824
    ushort* Wt   = (ushort*)(ws + 25165824);     //    884,736
    float*  peT  = (float*)(ws + 26050560);      //  1,572,864
    ushort* Qb   = (ushort*)(ws + 27623424);     // 25,165,824
    ushort* Ktl  = (ushort*)(ws + 52789248);     // 25,165,824
    ushort* Vtl  = (ushort*)(ws + 77955072);     // 25,165,824  (total 103,120,896)

    pe_kernel<<<1536, 256, 0, stream>>>(peT);
    wt_kernel<<<dim3(36, 12), dim3(32, 8), 0, stream>>>(W, Wt);
    astage_kernel<<<dim3(32, 12, 32), dim3(32, 8), 0, stream>>>(x, peT, A_bf);
    qkv_gemm<<<2304, 256, 0, stream>>>(A_bf, Wt, bias, Qb, Ktl, Vtl);
    attn_kernel<<<512, 512, 0, stream>>>(Qb, Ktl, Vtl, out);
}

// Round 12
// 139.070 us; speedup vs baseline: 1.1585x; 1.1585x over previous
//
#include <hip/hip_runtime.h>
#include <hip/hip_bf16.h>
#include <math.h>

typedef __attribute__((ext_vector_type(8))) __bf16 bf16x8;
typedef __attribute__((ext_vector_type(4))) float f32x4;

#define S_LEN 1024
#define D_MODEL 384
#define BATCH 32
#define N3 1152
#define KVB 32
#define NT (S_LEN / KVB)

#define MFMA16(a, b, c) __builtin_amdgcn_mfma_f32_16x16x32_bf16((a), (b), (c), 0, 0, 0)

static __device__ __forceinline__ ushort f2bf(float f) {
    __bf16 h = (__bf16)f;
    return __builtin_bit_cast(ushort, h);
}
static __device__ __forceinline__ float exp2a(float x) {
    float r; asm("v_exp_f32 %0, %1" : "=v"(r) : "v"(x)); return r;
}
static __device__ __forceinline__ uint cvtpk(float a, float b) {
    uint r; asm("v_cvt_pk_bf16_f32 %0, %1, %2" : "=v"(r) : "v"(a), "v"(b)); return r;
}

// ---------------- kernel 1: positional-encoding table, transposed peT[k][s] ----
__global__ void pe_kernel(float* peT) {
    int idx = blockIdx.x * 256 + threadIdx.x;      // 384*1024 total
    int k = idx >> 10, s = idx & 1023;
    float e = -(float)((k >> 1) * 2) * (logf(10000.0f) / (float)D_MODEL);
    float div = expf(e);
    float a = (float)s * div;
    peT[idx] = (k & 1) ? cosf(a) : sinf(a);
}

// ---------------- kernel 2: W [384][1152] f32 -> Wt [1152][384] bf16 ----------
__global__ void wt_kernel(const float* __restrict__ W, ushort* __restrict__ Wt) {
    __shared__ float tile[32][33];
    int n0 = blockIdx.x * 32, k0 = blockIdx.y * 32;
    int tx = threadIdx.x, ty = threadIdx.y;
#pragma unroll
    for (int r = 0; r < 4; ++r) {
        int kl = ty * 4 + r;
        tile[kl][tx] = W[(size_t)(k0 + kl) * N3 + n0 + tx];
    }
    __syncthreads();
#pragma unroll
    for (int r = 0; r < 4; ++r) {
        int nl = ty * 4 + r;
        Wt[(size_t)(n0 + nl) * D_MODEL + k0 + tx] = f2bf(tile[tx][nl]);
    }
}

// ---------------- kernel 3: A[m][k] = bf16(x[b][k][s] + peT[k][s]) ------------
__global__ void astage_kernel(const float* __restrict__ x, const float* __restrict__ peT,
                              ushort* __restrict__ A) {
    __shared__ float tile[32][33];
    int s0 = blockIdx.x * 32, k0 = blockIdx.y * 32, b = blockIdx.z;
    int tx = threadIdx.x, ty = threadIdx.y;
#pragma unroll
    for (int r = 0; r < 4; ++r) {
        int kl = ty * 4 + r;
        tile[kl][tx] = x[(size_t)(b * D_MODEL + k0 + kl) * S_LEN + s0 + tx]
                     + peT[(size_t)(k0 + kl) * S_LEN + s0 + tx];
    }
    __syncthreads();
#pragma unroll
    for (int r = 0; r < 4; ++r) {
        int sl = ty * 4 + r;
        A[(size_t)(b * S_LEN + s0 + sl) * D_MODEL + k0 + tx] = f2bf(tile[tx][sl]);
    }
}

// ---------------- kernel 4: qkv GEMM -> Q rows + pre-tiled/swizzled K,V panels
// (v9-verbatim, KVB=32 panels.)
// K_tiled[b][t32][j 32][384k]: row 768B, 16B-slot XOR (k>>3)^(j&7) baked.
// V_tiled[b][t32][c 384][j 32]: row 64B,  16B-slot XOR (j>>3)^((c>>1)&3).
__global__ __launch_bounds__(256) void qkv_gemm(const ushort* __restrict__ A,
                                                const ushort* __restrict__ Wt,
                                                const float* __restrict__ bias,
                                                ushort* __restrict__ Qb,
                                                ushort* __restrict__ Ktl,
                                                ushort* __restrict__ Vtl) {
    __shared__ __align__(16) ushort As[128 * 32];
    __shared__ __align__(16) ushort Bs[128 * 32];
    int id = blockIdx.x;                  // 2304 = 8 chunks * (9 n * 32 m)
    int g = id / 288, loc = id % 288;
    int nt_ = loc / 32, mt_ = g * 32 + (loc % 32);
    int m0 = mt_ * 128, n0 = nt_ * 128;
    int tid = threadIdx.x;
    int wave = tid >> 6, lane = tid & 63;
    int i16 = lane & 15, gq = lane >> 4;
    int wr = wave >> 1, wc = wave & 1;
    f32x4 acc[4][4] = {};
    for (int ks = 0; ks < 12; ++ks) {
        int k0 = ks * 32;
        __syncthreads();
#pragma unroll
        for (int i = 0; i < 2; ++i) {
            int off = (wave * 2 + i) * 1024;
            int row = (off >> 6) + (lane >> 2);
            int kc = lane & 3;
            const ushort* ga = A + (size_t)(m0 + row) * D_MODEL + k0 + kc * 8;
            __builtin_amdgcn_global_load_lds(
                (const __attribute__((address_space(1))) uint32_t*)ga,
                (__attribute__((address_space(3))) uint32_t*)((char*)As + off), 16, 0, 0);
            const ushort* gb = Wt + (size_t)(n0 + row) * D_MODEL + k0 + kc * 8;
            __builtin_amdgcn_global_load_lds(
                (const __attribute__((address_space(1))) uint32_t*)gb,
                (__attribute__((address_space(3))) uint32_t*)((char*)Bs + off), 16, 0, 0);
        }
        __syncthreads();
        bf16x8 af[4], bfr[4];
#pragma unroll
        for (int mt = 0; mt < 4; ++mt) {
            int row = wr * 64 + mt * 16 + i16;
            af[mt] = *reinterpret_cast<const bf16x8*>(&As[row * 32 + gq * 8]);
        }
#pragma unroll
        for (int nt = 0; nt < 4; ++nt) {
            int row = wc * 64 + nt * 16 + i16;
            bfr[nt] = *reinterpret_cast<const bf16x8*>(&Bs[row * 32 + gq * 8]);
        }
#pragma unroll
        for (int mt = 0; mt < 4; ++mt)
#pragma unroll
            for (int nt = 0; nt < 4; ++nt)
                acc[mt][nt] = MFMA16(af[mt], bfr[nt], acc[mt][nt]);
    }
    if (n0 < D_MODEL) {
#pragma unroll
        for (int nt = 0; nt < 4; ++nt) {
            int n = n0 + wc * 64 + nt * 16 + i16;
            float bv = bias[n];
#pragma unroll
            for (int mt = 0; mt < 4; ++mt)
#pragma unroll
                for (int r = 0; r < 4; ++r) {
                    int m = m0 + wr * 64 + mt * 16 + gq * 4 + r;
                    Qb[(size_t)m * D_MODEL + n] = f2bf(acc[mt][nt][r] + bv);
                }
        }
    } else if (n0 < 2 * D_MODEL) {
        int b = m0 >> 10;
#pragma unroll
        for (int nt = 0; nt < 4; ++nt) {
            int n = n0 + wc * 64 + nt * 16 + i16;
            float bv = bias[n];
            int k2 = n - D_MODEL;
            int slotk = k2 >> 3, within = k2 & 7;
#pragma unroll
            for (int mt = 0; mt < 4; ++mt)
#pragma unroll
                for (int r = 0; r < 4; ++r) {
                    int m = m0 + wr * 64 + mt * 16 + gq * 4 + r;
                    int s = m & 1023;
                    int t = s >> 5, j = s & 31;
                    size_t idx = (size_t)(b * 32 + t) * 12288 + j * 384
                               + (((slotk ^ (j & 7)) << 3) + within);
                    Ktl[idx] = f2bf(acc[mt][nt][r] + bv);
                }
        }
    } else {
        int b = m0 >> 10;
#pragma unroll
        for (int nt = 0; nt < 4; ++nt) {
            int n = n0 + wc * 64 + nt * 16 + i16;
            float bv = bias[n];
            int c = n - 2 * D_MODEL;
            int cx = (c >> 1) & 3;
#pragma unroll
            for (int mt = 0; mt < 4; ++mt) {
                int m = m0 + wr * 64 + mt * 16 + gq * 4;
                int s = m & 1023;
                int t = s >> 5, j = s & 31;       // j % 4 == 0
                size_t idx = (size_t)(b * 32 + t) * 12288 + c * 32
                           + ((((j >> 3) ^ cx) << 3) + (j & 7));
                ushort4 p4;
                p4.x = f2bf(acc[mt][nt][0] + bv);
                p4.y = f2bf(acc[mt][nt][1] + bv);
                p4.z = f2bf(acc[mt][nt][2] + bv);
                p4.w = f2bf(acc[mt][nt][3] + bv);
                *reinterpret_cast<ushort4*>(&Vtl[idx]) = p4;
            }
        }
    }
}

// ---------------- kernel 5: flash attention v12 — wave-specialized -----------
// 256 blocks (1/CU, single round), 8 waves, blockQ=128, KVB=32.
// Waves 0-3 = QK (qg, W=32, Q in 96 VGPR, no O): compute P(t+1) one tile ahead,
//   write Pb[(t+1)&1] (bank-XOR'd), accumulate l.
// Waves 4-7 = PV (cs c-slice 96, W=128 on P side, O in 192 VGPR, no Q): each
//   V-fragment feeds 8 MFMAs; every V-byte read ONCE from LDS.
// LDS 112 KB: Kb[2]x24K | Vb[2]x24K | Pb[2]x8K. One barrier/tile, matched
// barrier counts in both role loops (AMD s_barrier is position-independent).
// Stages issued at iter top (full tile to land); vmcnt(0)+lgkm(0) at loop top.
__global__ __launch_bounds__(512, 1) void attn_kernel(const ushort* __restrict__ Qb,
                                                      const ushort* __restrict__ Ktl,
                                                      const ushort* __restrict__ Vtl,
                                                      float* __restrict__ out) {
    __shared__ __align__(16) char smem[114688];
    // Kb[bi] @ bi*24576 ; Vb[bi] @ 49152 + bi*24576 ; Pb[bi] @ 98304 + bi*8192
    int id = blockIdx.x;                               // 256 = 8 qt * 4 slot * 8 xcd
    int xcd = id & 7, slot = (id >> 3) & 3, qt = id >> 5;
    int b = slot * 8 + xcd;                            // batch grouped per XCD
    int q0blk = qt * 128;
    int tid = threadIdx.x;
    int wave = tid >> 6, lane = tid & 63;
    int i16 = lane & 15, gq = lane >> 4;
    int w2 = wave & 3;
    const float sl2e = 0.05103103630798287f * 1.4426950408889634f;

    auto stage_K = [&](int tt, int bi) {
        const ushort* pan = Ktl + (size_t)(b * 32 + tt) * 12288;
        char* dst = smem + bi * 24576;
#pragma unroll
        for (int r = 0; r < 3; ++r) {
            int ii = wave * 3 + r;                     // 0..23
            const ushort* ga = pan + ii * 512 + lane * 8;
            __builtin_amdgcn_global_load_lds(
                (const __attribute__((address_space(1))) uint32_t*)ga,
                (__attribute__((address_space(3))) uint32_t*)(dst + ii * 1024), 16, 0, 0);
        }
    };
    auto stage_V = [&](int tt, int bi) {
        const ushort* pan = Vtl + (size_t)(b * 32 + tt) * 12288;
        char* dst = smem + 49152 + bi * 24576;
#pragma unroll
        for (int r = 0; r < 3; ++r) {
            int ii = wave * 3 + r;
            const ushort* ga = pan + ii * 512 + lane * 8;
            __builtin_amdgcn_global_load_lds(
                (const __attribute__((address_space(1))) uint32_t*)ga,
                (__attribute__((address_space(3))) uint32_t*)(dst + ii * 1024), 16, 0, 0);
        }
    };

    stage_K(0, 0);                                     // K(0) -> Kb[0] (all waves)
    asm volatile("s_waitcnt vmcnt(0)" ::: "memory");
    __syncthreads();                                   // barrier A (convergent)

    if (wave < 4) {
        // ================= QK role: wave qg owns q-block qg (32 q) ===========
        int qg = w2;
        bf16x8 qf[12][2];
        const ushort* Q0 = Qb + (size_t)(b * S_LEN + q0blk + qg * 32 + i16) * D_MODEL;
        const ushort* Q1 = Q0 + (size_t)16 * D_MODEL;
#pragma unroll
        for (int kt = 0; kt < 12; ++kt) {
            qf[kt][0] = *reinterpret_cast<const bf16x8*>(Q0 + kt * 32 + gq * 8);
            qf[kt][1] = *reinterpret_cast<const bf16x8*>(Q1 + kt * 32 + gq * 8);
        }
        float lsum0 = 0.f, lsum1 = 0.f;
        int jc0 = gq >> 1, jc1 = 2 + (gq >> 1);
        int q0 = qg * 32 + i16, q1 = qg * 32 + 16 + i16;

        auto qk_step = [&](int tt) {
            const char* Kb = smem + (tt & 1) * 24576;
            char* Pw = smem + 98304 + (tt & 1) * 8192;
            f32x4 s00 = {}, s01 = {}, s10 = {}, s11 = {};
            __builtin_amdgcn_s_setprio(1);
#pragma unroll
            for (int kt = 0; kt < 12; ++kt) {
                int kc = (kt * 64 + gq * 16) ^ ((i16 & 7) << 4);
                bf16x8 kf0 = *reinterpret_cast<const bf16x8*>(Kb + i16 * 768 + kc);
                bf16x8 kf1 = *reinterpret_cast<const bf16x8*>(Kb + (16 + i16) * 768 + kc);
                s00 = MFMA16(kf0, qf[kt][0], s00);
                s01 = MFMA16(kf0, qf[kt][1], s01);
                s10 = MFMA16(kf1, qf[kt][0], s10);
                s11 = MFMA16(kf1, qf[kt][1], s11);
            }
            __builtin_amdgcn_s_setprio(0);
            // drop-max softmax; write P[j][q] at (j>>3)*2048 + ((q*16)^(((j>>3)&3)<<4)) + (j&7)*2
            {
                float p0 = exp2a(s00[0] * sl2e), p1 = exp2a(s00[1] * sl2e);
                float p2 = exp2a(s00[2] * sl2e), p3 = exp2a(s00[3] * sl2e);
                lsum0 += (p0 + p1) + (p2 + p3);
                uint2 w; w.x = cvtpk(p0, p1); w.y = cvtpk(p2, p3);
                *reinterpret_cast<uint2*>(Pw + jc0 * 2048 + ((q0 * 16) ^ ((jc0 & 3) << 4)) + (gq & 1) * 8) = w;
            }
            {
                float p0 = exp2a(s01[0] * sl2e), p1 = exp2a(s01[1] * sl2e);
                float p2 = exp2a(s01[2] * sl2e), p3 = exp2a(s01[3] * sl2e);
                lsum1 += (p0 + p1) + (p2 + p3);
                uint2 w; w.x = cvtpk(p0, p1); w.y = cvtpk(p2, p3);
                *reinterpret_cast<uint2*>(Pw + jc0 * 2048 + ((q1 * 16) ^ ((jc0 & 3) << 4)) + (gq & 1) * 8) = w;
            }
            {
                float p0 = exp2a(s10[0] * sl2e), p1 = exp2a(s10[1] * sl2e);
                float p2 = exp2a(s10[2] * sl2e), p3 = exp2a(s10[3] * sl2e);
                lsum0 += (p0 + p1) + (p2 + p3);
                uint2 w; w.x = cvtpk(p0, p1); w.y = cvtpk(p2, p3);
                *reinterpret_cast<uint2*>(Pw + jc1 * 2048 + ((q0 * 16) ^ ((jc1 & 3) << 4)) + (gq & 1) * 8) = w;
            }
            {
                float p0 = exp2a(s11[0] * sl2e), p1 = exp2a(s11[1] * sl2e);
                float p2 = exp2a(s11[2] * sl2e), p3 = exp2a(s11[3] * sl2e);
                lsum1 += (p0 + p1) + (p2 + p3);
                uint2 w; w.x = cvtpk(p0, p1); w.y = cvtpk(p2, p3);
                *reinterpret_cast<uint2*>(Pw + jc1 * 2048 + ((q1 * 16) ^ ((jc1 & 3) << 4)) + (gq & 1) * 8) = w;
            }
        };

        qk_step(0);                                    // P(0) -> Pb[0]
        stage_K(1, 1);
        stage_V(0, 0);
        asm volatile("s_waitcnt lgkmcnt(0)" ::: "memory");
        __builtin_amdgcn_s_barrier();                  // B#1
        for (int t = 0; t < NT; ++t) {
            asm volatile("s_waitcnt vmcnt(0) lgkmcnt(0)" ::: "memory");
            __builtin_amdgcn_s_barrier();              // B#2+t
            __builtin_amdgcn_sched_barrier(0);
            if (t + 2 < NT) stage_K(t + 2, t & 1);
            if (t + 1 < NT) stage_V(t + 1, (t + 1) & 1);
            if (t + 1 < NT) qk_step(t + 1);
        }
        __syncthreads();                               // B#2+NT
        lsum0 += __shfl_xor(lsum0, 16); lsum0 += __shfl_xor(lsum0, 32);
        lsum1 += __shfl_xor(lsum1, 16); lsum1 += __shfl_xor(lsum1, 32);
        float* Lt = reinterpret_cast<float*>(smem + 98304);
        if (gq == 0) {
            Lt[qg * 32 + i16] = lsum0;
            Lt[qg * 32 + 16 + i16] = lsum1;
        }
        __syncthreads();                               // B#3+NT
    } else {
        // ================= PV role: wave cs owns c-slice cs*96..+96 ==========
        int cs = w2;
        f32x4 oc[6][8] = {};
        stage_K(1, 1);
        stage_V(0, 0);
        asm volatile("s_waitcnt lgkmcnt(0)" ::: "memory");
        __builtin_amdgcn_s_barrier();                  // B#1
        for (int t = 0; t < NT; ++t) {
            asm volatile("s_waitcnt vmcnt(0) lgkmcnt(0)" ::: "memory");
            __builtin_amdgcn_s_barrier();              // B#2+t
            __builtin_amdgcn_sched_barrier(0);
            if (t + 2 < NT) stage_K(t + 2, t & 1);
            if (t + 1 < NT) stage_V(t + 1, (t + 1) & 1);
            const char* Vb = smem + 49152 + (t & 1) * 24576;
            const char* Pb = smem + 98304 + (t & 1) * 8192;
            bf16x8 pf[8];
#pragma unroll
            for (int qs = 0; qs < 8; ++qs) {
                int q = qs * 16 + i16;
                pf[qs] = *reinterpret_cast<const bf16x8*>(
                    Pb + gq * 2048 + ((q * 16) ^ ((gq & 3) << 4)));
            }
            __builtin_amdgcn_s_setprio(1);
#pragma unroll
            for (int ct = 0; ct < 6; ++ct) {
                int c = cs * 96 + ct * 16 + i16;
                bf16x8 vf = *reinterpret_cast<const bf16x8*>(
                    Vb + c * 64 + ((gq * 16) ^ (((i16 >> 1) & 3) << 4)));
                oc[ct][0] = MFMA16(vf, pf[0], oc[ct][0]);
                oc[ct][1] = MFMA16(vf, pf[1], oc[ct][1]);
                oc[ct][2] = MFMA16(vf, pf[2], oc[ct][2]);
                oc[ct][3] = MFMA16(vf, pf[3], oc[ct][3]);
                oc[ct][4] = MFMA16(vf, pf[4], oc[ct][4]);
                oc[ct][5] = MFMA16(vf, pf[5], oc[ct][5]);
                oc[ct][6] = MFMA16(vf, pf[6], oc[ct][6]);
                oc[ct][7] = MFMA16(vf, pf[7], oc[ct][7]);
            }
            __builtin_amdgcn_s_setprio(0);
        }
        __syncthreads();                               // B#2+NT
        __syncthreads();                               // B#3+NT (Ltab now valid)
        const float* Lt = reinterpret_cast<const float*>(smem + 98304);
        float* ob = out + (size_t)b * D_MODEL * S_LEN + q0blk;
#pragma unroll
        for (int qs = 0; qs < 8; ++qs) {
            float inv = 1.0f / Lt[qs * 16 + i16];
#pragma unroll
            for (int ct = 0; ct < 6; ++ct)
#pragma unroll
                for (int r = 0; r < 4; ++r) {
                    int c = cs * 96 + ct * 16 + gq * 4 + r;
                    ob[(size_t)c * S_LEN + qs * 16 + i16] = oc[ct][qs][r] * inv;
                }
        }
    }
}

extern "C" void kernel_launch(void* const* d_in, const int* in_sizes, int n_in,
                              void* d_out, int out_size, void* d_ws, size_t ws_size,
                              hipStream_t stream) {
    const float* x    = (const float*)d_in[0];
    const float* W    = (const float*)d_in[1];
    const float* bias = (const float*)d_in[2];
    float* out = (float*)d_out;

    char* ws = (char*)d_ws;
    ushort* A_bf = (ushort*)(ws);                // 25,165,824
    ushort* Wt   = (ushort*)(ws + 25165824);     //    884,736
    float*  peT  = (float*)(ws + 26050560);      //  1,572,864
    ushort* Qb   = (ushort*)(ws + 27623424);     // 25,165,824
    ushort* Ktl  = (ushort*)(ws + 52789248);     // 25,165,824
    ushort* Vtl  = (ushort*)(ws + 77955072);     // 25,165,824  (total 103,120,896)

    pe_kernel<<<1536, 256, 0, stream>>>(peT);
    wt_kernel<<<dim3(36, 12), dim3(32, 8), 0, stream>>>(W, Wt);
    astage_kernel<<<dim3(32, 12, 32), dim3(32, 8), 0, stream>>>(x, peT, A_bf);
    qkv_gemm<<<2304, 256, 0, stream>>>(A_bf, Wt, bias, Qb, Ktl, Vtl);
    attn_kernel<<<256, 512, 0, stream>>>(Qb, Ktl, Vtl, out);
}

// Round 13
// 133.386 us; speedup vs baseline: 1.2078x; 1.0426x over previous
//
#include <hip/hip_runtime.h>
#include <hip/hip_bf16.h>
#include <math.h>

typedef __attribute__((ext_vector_type(8))) __bf16 bf16x8;
typedef __attribute__((ext_vector_type(4))) float f32x4;

#define S_LEN 1024
#define D_MODEL 384
#define BATCH 32
#define N3 1152
#define KVB 32
#define NT (S_LEN / KVB)

#define MFMA16(a, b, c) __builtin_amdgcn_mfma_f32_16x16x32_bf16((a), (b), (c), 0, 0, 0)

static __device__ __forceinline__ ushort f2bf(float f) {
    __bf16 h = (__bf16)f;
    return __builtin_bit_cast(ushort, h);
}
static __device__ __forceinline__ float exp2a(float x) {
    float r; asm("v_exp_f32 %0, %1" : "=v"(r) : "v"(x)); return r;
}
static __device__ __forceinline__ uint cvtpk(float a, float b) {
    uint r; asm("v_cvt_pk_bf16_f32 %0, %1, %2" : "=v"(r) : "v"(a), "v"(b)); return r;
}

// ---------------- kernel 1: positional-encoding table, transposed peT[k][s] ----
__global__ void pe_kernel(float* peT) {
    int idx = blockIdx.x * 256 + threadIdx.x;      // 384*1024 total
    int k = idx >> 10, s = idx & 1023;
    float e = -(float)((k >> 1) * 2) * (logf(10000.0f) / (float)D_MODEL);
    float div = expf(e);
    float a = (float)s * div;
    peT[idx] = (k & 1) ? cosf(a) : sinf(a);
}

// ---------------- kernel 2: W [384][1152] f32 -> Wt [1152][384] bf16 ----------
__global__ void wt_kernel(const float* __restrict__ W, ushort* __restrict__ Wt) {
    __shared__ float tile[32][33];
    int n0 = blockIdx.x * 32, k0 = blockIdx.y * 32;
    int tx = threadIdx.x, ty = threadIdx.y;
#pragma unroll
    for (int r = 0; r < 4; ++r) {
        int kl = ty * 4 + r;
        tile[kl][tx] = W[(size_t)(k0 + kl) * N3 + n0 + tx];
    }
    __syncthreads();
#pragma unroll
    for (int r = 0; r < 4; ++r) {
        int nl = ty * 4 + r;
        Wt[(size_t)(n0 + nl) * D_MODEL + k0 + tx] = f2bf(tile[tx][nl]);
    }
}

// ---------------- kernel 3: A[m][k] = bf16(x[b][k][s] + peT[k][s]) ------------
__global__ void astage_kernel(const float* __restrict__ x, const float* __restrict__ peT,
                              ushort* __restrict__ A) {
    __shared__ float tile[32][33];
    int s0 = blockIdx.x * 32, k0 = blockIdx.y * 32, b = blockIdx.z;
    int tx = threadIdx.x, ty = threadIdx.y;
#pragma unroll
    for (int r = 0; r < 4; ++r) {
        int kl = ty * 4 + r;
        tile[kl][tx] = x[(size_t)(b * D_MODEL + k0 + kl) * S_LEN + s0 + tx]
                     + peT[(size_t)(k0 + kl) * S_LEN + s0 + tx];
    }
    __syncthreads();
#pragma unroll
    for (int r = 0; r < 4; ++r) {
        int sl = ty * 4 + r;
        A[(size_t)(b * S_LEN + s0 + sl) * D_MODEL + k0 + tx] = f2bf(tile[tx][sl]);
    }
}

// ---------------- kernel 4: qkv GEMM -> Q rows + pre-tiled/swizzled K,V panels
// (v9-verbatim.) K_tiled[b][t32][j 32][384k] XOR (k>>3)^(j&7) baked;
// V_tiled[b][t32][c 384][j 32] XOR (j>>3)^((c>>1)&3) baked.
__global__ __launch_bounds__(256) void qkv_gemm(const ushort* __restrict__ A,
                                                const ushort* __restrict__ Wt,
                                                const float* __restrict__ bias,
                                                ushort* __restrict__ Qb,
                                                ushort* __restrict__ Ktl,
                                                ushort* __restrict__ Vtl) {
    __shared__ __align__(16) ushort As[128 * 32];
    __shared__ __align__(16) ushort Bs[128 * 32];
    int id = blockIdx.x;                  // 2304 = 8 chunks * (9 n * 32 m)
    int g = id / 288, loc = id % 288;
    int nt_ = loc / 32, mt_ = g * 32 + (loc % 32);
    int m0 = mt_ * 128, n0 = nt_ * 128;
    int tid = threadIdx.x;
    int wave = tid >> 6, lane = tid & 63;
    int i16 = lane & 15, gq = lane >> 4;
    int wr = wave >> 1, wc = wave & 1;
    f32x4 acc[4][4] = {};
    for (int ks = 0; ks < 12; ++ks) {
        int k0 = ks * 32;
        __syncthreads();
#pragma unroll
        for (int i = 0; i < 2; ++i) {
            int off = (wave * 2 + i) * 1024;
            int row = (off >> 6) + (lane >> 2);
            int kc = lane & 3;
            const ushort* ga = A + (size_t)(m0 + row) * D_MODEL + k0 + kc * 8;
            __builtin_amdgcn_global_load_lds(
                (const __attribute__((address_space(1))) uint32_t*)ga,
                (__attribute__((address_space(3))) uint32_t*)((char*)As + off), 16, 0, 0);
            const ushort* gb = Wt + (size_t)(n0 + row) * D_MODEL + k0 + kc * 8;
            __builtin_amdgcn_global_load_lds(
                (const __attribute__((address_space(1))) uint32_t*)gb,
                (__attribute__((address_space(3))) uint32_t*)((char*)Bs + off), 16, 0, 0);
        }
        __syncthreads();
        bf16x8 af[4], bfr[4];
#pragma unroll
        for (int mt = 0; mt < 4; ++mt) {
            int row = wr * 64 + mt * 16 + i16;
            af[mt] = *reinterpret_cast<const bf16x8*>(&As[row * 32 + gq * 8]);
        }
#pragma unroll
        for (int nt = 0; nt < 4; ++nt) {
            int row = wc * 64 + nt * 16 + i16;
            bfr[nt] = *reinterpret_cast<const bf16x8*>(&Bs[row * 32 + gq * 8]);
        }
#pragma unroll
        for (int mt = 0; mt < 4; ++mt)
#pragma unroll
            for (int nt = 0; nt < 4; ++nt)
                acc[mt][nt] = MFMA16(af[mt], bfr[nt], acc[mt][nt]);
    }
    if (n0 < D_MODEL) {
#pragma unroll
        for (int nt = 0; nt < 4; ++nt) {
            int n = n0 + wc * 64 + nt * 16 + i16;
            float bv = bias[n];
#pragma unroll
            for (int mt = 0; mt < 4; ++mt)
#pragma unroll
                for (int r = 0; r < 4; ++r) {
                    int m = m0 + wr * 64 + mt * 16 + gq * 4 + r;
                    Qb[(size_t)m * D_MODEL + n] = f2bf(acc[mt][nt][r] + bv);
                }
        }
    } else if (n0 < 2 * D_MODEL) {
        int b = m0 >> 10;
#pragma unroll
        for (int nt = 0; nt < 4; ++nt) {
            int n = n0 + wc * 64 + nt * 16 + i16;
            float bv = bias[n];
            int k2 = n - D_MODEL;
            int slotk = k2 >> 3, within = k2 & 7;
#pragma unroll
            for (int mt = 0; mt < 4; ++mt)
#pragma unroll
                for (int r = 0; r < 4; ++r) {
                    int m = m0 + wr * 64 + mt * 16 + gq * 4 + r;
                    int s = m & 1023;
                    int t = s >> 5, j = s & 31;
                    size_t idx = (size_t)(b * 32 + t) * 12288 + j * 384
                               + (((slotk ^ (j & 7)) << 3) + within);
                    Ktl[idx] = f2bf(acc[mt][nt][r] + bv);
                }
        }
    } else {
        int b = m0 >> 10;
#pragma unroll
        for (int nt = 0; nt < 4; ++nt) {
            int n = n0 + wc * 64 + nt * 16 + i16;
            float bv = bias[n];
            int c = n - 2 * D_MODEL;
            int cx = (c >> 1) & 3;
#pragma unroll
            for (int mt = 0; mt < 4; ++mt) {
                int m = m0 + wr * 64 + mt * 16 + gq * 4;
                int s = m & 1023;
                int t = s >> 5, j = s & 31;       // j % 4 == 0
                size_t idx = (size_t)(b * 32 + t) * 12288 + c * 32
                           + ((((j >> 3) ^ cx) << 3) + (j & 7));
                ushort4 p4;
                p4.x = f2bf(acc[mt][nt][0] + bv);
                p4.y = f2bf(acc[mt][nt][1] + bv);
                p4.z = f2bf(acc[mt][nt][2] + bv);
                p4.w = f2bf(acc[mt][nt][3] + bv);
                *reinterpret_cast<ushort4*>(&Vtl[idx]) = p4;
            }
        }
    }
}

// ---------------- kernel 5: flash attention v13 — wave-specialized, 12 waves -
// 256 blocks (1/CU), 768 threads = 12 waves -> 3 waves/SIMD (1 QK + 2 PV each):
// QK's ds_read/softmax stalls covered by TWO independent PV MFMA streams.
// Waves 0-3 = QK (qg, W=32, Q in 96 VGPR): P(t+1) one tile ahead -> Pb[(t+1)&1].
// Waves 4-11 = PV (cs c-slice 48, W=128 on P side, O in 96 VGPR): each V-frag
// feeds 8 MFMAs. LDS 112 KB: Kb[2]x24K | Vb[2]x24K | Pb[2]x8K. One barrier/tile,
// matched counts in both role branches. Stage chunks: 24 = 12 waves x 2.
__global__ __launch_bounds__(768, 1) void attn_kernel(const ushort* __restrict__ Qb,
                                                      const ushort* __restrict__ Ktl,
                                                      const ushort* __restrict__ Vtl,
                                                      float* __restrict__ out) {
    __shared__ __align__(16) char smem[114688];
    // Kb[bi] @ bi*24576 ; Vb[bi] @ 49152 + bi*24576 ; Pb[bi] @ 98304 + bi*8192
    int id = blockIdx.x;                               // 256 = 8 qt * 4 slot * 8 xcd
    int xcd = id & 7, slot = (id >> 3) & 3, qt = id >> 5;
    int b = slot * 8 + xcd;                            // batch grouped per XCD
    int q0blk = qt * 128;
    int tid = threadIdx.x;
    int wave = tid >> 6, lane = tid & 63;
    int i16 = lane & 15, gq = lane >> 4;
    const float sl2e = 0.05103103630798287f * 1.4426950408889634f;

    auto stage_K = [&](int tt, int bi) {
        const ushort* pan = Ktl + (size_t)(b * 32 + tt) * 12288;
        char* dst = smem + bi * 24576;
#pragma unroll
        for (int r = 0; r < 2; ++r) {
            int ii = wave * 2 + r;                     // 0..23
            const ushort* ga = pan + ii * 512 + lane * 8;
            __builtin_amdgcn_global_load_lds(
                (const __attribute__((address_space(1))) uint32_t*)ga,
                (__attribute__((address_space(3))) uint32_t*)(dst + ii * 1024), 16, 0, 0);
        }
    };
    auto stage_V = [&](int tt, int bi) {
        const ushort* pan = Vtl + (size_t)(b * 32 + tt) * 12288;
        char* dst = smem + 49152 + bi * 24576;
#pragma unroll
        for (int r = 0; r < 2; ++r) {
            int ii = wave * 2 + r;
            const ushort* ga = pan + ii * 512 + lane * 8;
            __builtin_amdgcn_global_load_lds(
                (const __attribute__((address_space(1))) uint32_t*)ga,
                (__attribute__((address_space(3))) uint32_t*)(dst + ii * 1024), 16, 0, 0);
        }
    };

    stage_K(0, 0);                                     // K(0) -> Kb[0] (all waves)
    asm volatile("s_waitcnt vmcnt(0)" ::: "memory");
    __syncthreads();                                   // barrier A (convergent)

    if (wave < 4) {
        // ================= QK role: wave qg owns q-block qg (32 q) ===========
        int qg = wave;
        bf16x8 qf[12][2];
        const ushort* Q0 = Qb + (size_t)(b * S_LEN + q0blk + qg * 32 + i16) * D_MODEL;
        const ushort* Q1 = Q0 + (size_t)16 * D_MODEL;
#pragma unroll
        for (int kt = 0; kt < 12; ++kt) {
            qf[kt][0] = *reinterpret_cast<const bf16x8*>(Q0 + kt * 32 + gq * 8);
            qf[kt][1] = *reinterpret_cast<const bf16x8*>(Q1 + kt * 32 + gq * 8);
        }
        float lsum0 = 0.f, lsum1 = 0.f;
        int jc0 = gq >> 1, jc1 = 2 + (gq >> 1);
        int q0 = qg * 32 + i16, q1 = qg * 32 + 16 + i16;

        auto qk_step = [&](int tt) {
            const char* Kb = smem + (tt & 1) * 24576;
            char* Pw = smem + 98304 + (tt & 1) * 8192;
            f32x4 s00 = {}, s01 = {}, s10 = {}, s11 = {};
            __builtin_amdgcn_s_setprio(1);
#pragma unroll
            for (int kt = 0; kt < 12; ++kt) {
                int kc = (kt * 64 + gq * 16) ^ ((i16 & 7) << 4);
                bf16x8 kf0 = *reinterpret_cast<const bf16x8*>(Kb + i16 * 768 + kc);
                bf16x8 kf1 = *reinterpret_cast<const bf16x8*>(Kb + (16 + i16) * 768 + kc);
                s00 = MFMA16(kf0, qf[kt][0], s00);
                s01 = MFMA16(kf0, qf[kt][1], s01);
                s10 = MFMA16(kf1, qf[kt][0], s10);
                s11 = MFMA16(kf1, qf[kt][1], s11);
            }
            __builtin_amdgcn_s_setprio(0);
            {
                float p0 = exp2a(s00[0] * sl2e), p1 = exp2a(s00[1] * sl2e);
                float p2 = exp2a(s00[2] * sl2e), p3 = exp2a(s00[3] * sl2e);
                lsum0 += (p0 + p1) + (p2 + p3);
                uint2 w; w.x = cvtpk(p0, p1); w.y = cvtpk(p2, p3);
                *reinterpret_cast<uint2*>(Pw + jc0 * 2048 + ((q0 * 16) ^ ((jc0 & 3) << 4)) + (gq & 1) * 8) = w;
            }
            {
                float p0 = exp2a(s01[0] * sl2e), p1 = exp2a(s01[1] * sl2e);
                float p2 = exp2a(s01[2] * sl2e), p3 = exp2a(s01[3] * sl2e);
                lsum1 += (p0 + p1) + (p2 + p3);
                uint2 w; w.x = cvtpk(p0, p1); w.y = cvtpk(p2, p3);
                *reinterpret_cast<uint2*>(Pw + jc0 * 2048 + ((q1 * 16) ^ ((jc0 & 3) << 4)) + (gq & 1) * 8) = w;
            }
            {
                float p0 = exp2a(s10[0] * sl2e), p1 = exp2a(s10[1] * sl2e);
                float p2 = exp2a(s10[2] * sl2e), p3 = exp2a(s10[3] * sl2e);
                lsum0 += (p0 + p1) + (p2 + p3);
                uint2 w; w.x = cvtpk(p0, p1); w.y = cvtpk(p2, p3);
                *reinterpret_cast<uint2*>(Pw + jc1 * 2048 + ((q0 * 16) ^ ((jc1 & 3) << 4)) + (gq & 1) * 8) = w;
            }
            {
                float p0 = exp2a(s11[0] * sl2e), p1 = exp2a(s11[1] * sl2e);
                float p2 = exp2a(s11[2] * sl2e), p3 = exp2a(s11[3] * sl2e);
                lsum1 += (p0 + p1) + (p2 + p3);
                uint2 w; w.x = cvtpk(p0, p1); w.y = cvtpk(p2, p3);
                *reinterpret_cast<uint2*>(Pw + jc1 * 2048 + ((q1 * 16) ^ ((jc1 & 3) << 4)) + (gq & 1) * 8) = w;
            }
        };

        qk_step(0);                                    // P(0) -> Pb[0]
        stage_K(1, 1);
        stage_V(0, 0);
        asm volatile("s_waitcnt lgkmcnt(0)" ::: "memory");
        __builtin_amdgcn_s_barrier();                  // B#1
        for (int t = 0; t < NT; ++t) {
            asm volatile("s_waitcnt vmcnt(0) lgkmcnt(0)" ::: "memory");
            __builtin_amdgcn_s_barrier();              // B#2+t
            __builtin_amdgcn_sched_barrier(0);
            if (t + 2 < NT) stage_K(t + 2, t & 1);
            if (t + 1 < NT) stage_V(t + 1, (t + 1) & 1);
            if (t + 1 < NT) qk_step(t + 1);
        }
        __syncthreads();                               // B#2+NT
        lsum0 += __shfl_xor(lsum0, 16); lsum0 += __shfl_xor(lsum0, 32);
        lsum1 += __shfl_xor(lsum1, 16); lsum1 += __shfl_xor(lsum1, 32);
        float* Lt = reinterpret_cast<float*>(smem + 98304);
        if (gq == 0) {
            Lt[qg * 32 + i16] = lsum0;
            Lt[qg * 32 + 16 + i16] = lsum1;
        }
        __syncthreads();                               // B#3+NT
    } else {
        // ================= PV role: wave cs owns c-slice cs*48..+48 ==========
        int cs = wave - 4;                             // 0..7
        f32x4 oc[3][8] = {};
        stage_K(1, 1);
        stage_V(0, 0);
        asm volatile("s_waitcnt lgkmcnt(0)" ::: "memory");
        __builtin_amdgcn_s_barrier();                  // B#1
        for (int t = 0; t < NT; ++t) {
            asm volatile("s_waitcnt vmcnt(0) lgkmcnt(0)" ::: "memory");
            __builtin_amdgcn_s_barrier();              // B#2+t
            __builtin_amdgcn_sched_barrier(0);
            if (t + 2 < NT) stage_K(t + 2, t & 1);
            if (t + 1 < NT) stage_V(t + 1, (t + 1) & 1);
            const char* Vb = smem + 49152 + (t & 1) * 24576;
            const char* Pb = smem + 98304 + (t & 1) * 8192;
            bf16x8 pf[8];
#pragma unroll
            for (int qs = 0; qs < 8; ++qs) {
                int q = qs * 16 + i16;
                pf[qs] = *reinterpret_cast<const bf16x8*>(
                    Pb + gq * 2048 + ((q * 16) ^ ((gq & 3) << 4)));
            }
            __builtin_amdgcn_s_setprio(1);
#pragma unroll
            for (int ct = 0; ct < 3; ++ct) {
                int c = cs * 48 + ct * 16 + i16;
                bf16x8 vf = *reinterpret_cast<const bf16x8*>(
                    Vb + c * 64 + ((gq * 16) ^ (((i16 >> 1) & 3) << 4)));
                oc[ct][0] = MFMA16(vf, pf[0], oc[ct][0]);
                oc[ct][1] = MFMA16(vf, pf[1], oc[ct][1]);
                oc[ct][2] = MFMA16(vf, pf[2], oc[ct][2]);
                oc[ct][3] = MFMA16(vf, pf[3], oc[ct][3]);
                oc[ct][4] = MFMA16(vf, pf[4], oc[ct][4]);
                oc[ct][5] = MFMA16(vf, pf[5], oc[ct][5]);
                oc[ct][6] = MFMA16(vf, pf[6], oc[ct][6]);
                oc[ct][7] = MFMA16(vf, pf[7], oc[ct][7]);
            }
            __builtin_amdgcn_s_setprio(0);
        }
        __syncthreads();                               // B#2+NT
        __syncthreads();                               // B#3+NT (Ltab now valid)
        const float* Lt = reinterpret_cast<const float*>(smem + 98304);
        float* ob = out + (size_t)b * D_MODEL * S_LEN + q0blk;
#pragma unroll
        for (int qs = 0; qs < 8; ++qs) {
            float inv = 1.0f / Lt[qs * 16 + i16];
#pragma unroll
            for (int ct = 0; ct < 3; ++ct)
#pragma unroll
                for (int r = 0; r < 4; ++r) {
                    int c = cs * 48 + ct * 16 + gq * 4 + r;
                    ob[(size_t)c * S_LEN + qs * 16 + i16] = oc[ct][qs][r] * inv;
                }
        }
    }
}

extern "C" void kernel_launch(void* const* d_in, const int* in_sizes, int n_in,
                              void* d_out, int out_size, void* d_ws, size_t ws_size,
                              hipStream_t stream) {
    const float* x    = (const float*)d_in[0];
    const float* W    = (const float*)d_in[1];
    const float* bias = (const float*)d_in[2];
    float* out = (float*)d_out;

    char* ws = (char*)d_ws;
    ushort* A_bf = (ushort*)(ws);                // 25,165,824
    ushort* Wt   = (ushort*)(ws + 25165824);     //    884,736
    float*  peT  = (float*)(ws + 26050560);      //  1,572,864
    ushort* Qb   = (ushort*)(ws + 27623424);     // 25,165,824
    ushort* Ktl  = (ushort*)(ws + 52789248);     // 25,165,824
    ushort* Vtl  = (ushort*)(ws + 77955072);     // 25,165,824  (total 103,120,896)

    pe_kernel<<<1536, 256, 0, stream>>>(peT);
    wt_kernel<<<dim3(36, 12), dim3(32, 8), 0, stream>>>(W, Wt);
    astage_kernel<<<dim3(32, 12, 32), dim3(32, 8), 0, stream>>>(x, peT, A_bf);
    qkv_gemm<<<2304, 256, 0, stream>>>(A_bf, Wt, bias, Qb, Ktl, Vtl);
    attn_kernel<<<256, 768, 0, stream>>>(Qb, Ktl, Vtl, out);
}